// Round 14
// baseline (292.759 us; speedup 1.0000x reference)
//
#include <hip/hip_runtime.h>
#include <hip/hip_bf16.h>
#include <stdint.h>

// Round 14: h never materializes. Swapped GEMM1 leaves h^T in acc regs; a
// k-permutation pi applied to BOTH GEMM2 operands (pi(lhi,i) = (i>=4)*16 +
// lhi*4 + (i&3)) lets the GEMM2 B-frag be built in place from acc1 (no
// shuffles, no h LDS). W2 is packed transposed with pi; Wi/W1 packs unchanged
// (A/B frag formulas coincide). GEMM3 swapped too -> out1^T dwordx4 stores.
// LDS 73.7->32KB (staging only) -> 3 blocks/CU at launch_bounds(256,3).
// Barrier skeleton = r12's proven __syncthreads structure.

typedef __attribute__((ext_vector_type(8))) short short8;
typedef __attribute__((ext_vector_type(4))) float float4v;

#define MFMA16 __builtin_amdgcn_mfma_f32_16x16x32_bf16

__device__ __align__(16) uint16_t g_wpack[98816];

static __device__ __forceinline__ void gl_lds16(const void* g, void* l) {
    __builtin_amdgcn_global_load_lds(
        (const __attribute__((address_space(1))) unsigned int*)g,
        (__attribute__((address_space(3))) unsigned int*)l, 16, 0, 0);
}

static __device__ __forceinline__ uint16_t f2bf(float f) {
    __hip_bfloat16 h = __float2bfloat16(f);
    return *reinterpret_cast<uint16_t*>(&h);
}

static __device__ __forceinline__ int pk2(float lo, float hi) {
    __hip_bfloat162 b = __float22bfloat162_rn(make_float2(lo, hi));
    int u; __builtin_memcpy(&u, &b, 4); return u;
}

static __device__ __forceinline__ short8 cvt8(float4v x0, float4v x1) {
    union { __hip_bfloat162 b2[4]; short8 s; } u;
    u.b2[0] = __float22bfloat162_rn(make_float2(x0[0], x0[1]));
    u.b2[1] = __float22bfloat162_rn(make_float2(x0[2], x0[3]));
    u.b2[2] = __float22bfloat162_rn(make_float2(x1[0], x1[1]));
    u.b2[3] = __float22bfloat162_rn(make_float2(x1[2], x1[3]));
    return u.s;
}

// ---- weight packing ----
// W1p: 9kt x 9nt std frags (K=288 pad, N=144 pad) @u16 0      (41472)
// W2Tp: pi-packed transposed, frag = p*40 + kt*8 + ntl @u16 41472 (40960)
//       slot(lane,i) = W2[kt*32 + (i>=4)*16 + (lane>>4)*4 + (i&3)][(p*8+ntl)*16 + (lane&15)]
// Wip: 16kt x 2nt std frags (K=512, N=32 pad) @u16 82432 (16384)
__global__ __launch_bounds__(256) void pack_weights(
    const float* __restrict__ W1, const float* __restrict__ W2,
    const float* __restrict__ Wi)
{
    int e = blockIdx.x * 256 + threadIdx.x;
    if (e >= 98816) return;
    if (e >= 41472 && e < 82432) {            // W2^T pi-packed
        int le = e - 41472;
        int i = le & 7, lane = (le >> 3) & 63, frag = le >> 9;   // 0..79
        int p = frag / 40, rem = frag - p * 40;
        int kt = rem >> 3, ntl = rem & 7;
        int k = kt * 32 + ((i >= 4) ? 16 : 0) + ((lane >> 4) << 2) + (i & 3);
        int n = (p * 8 + ntl) * 16 + (lane & 15);
        float v = (k < 140) ? W2[k * 256 + n] : 0.0f;
        g_wpack[e] = f2bf(v);
        return;
    }
    const float* W; int NT, Kr, Nr, ld, le, base;
    if (e < 41472) { W = W1; NT = 9; Kr = 280; Nr = 140; ld = 140; le = e;         base = 0; }
    else           { W = Wi; NT = 2; Kr = 512; Nr = 24;  ld = 24;  le = e - 82432; base = 82432; }
    int i = le & 7, lane = (le >> 3) & 63, frag = le >> 9;
    int kt = frag / NT, nt = frag - kt * NT;
    int k = kt * 32 + ((lane >> 4) << 3) + i;
    int n = nt * 16 + (lane & 15);
    float v = (k < Kr && n < Nr) ? W[k * ld + n] : 0.0f;
    g_wpack[base + le] = f2bf(v);
}

// ---- main fused kernel: 256 threads = 4 waves, each wave 32 rows ----
__global__ __launch_bounds__(256, 3) void icm_main(
    const float* __restrict__ cf, const float* __restrict__ nf,
    const int* __restrict__ act,
    const float* __restrict__ b1, const float* __restrict__ b2,
    const float* __restrict__ bi,
    float* __restrict__ out)
{
    __shared__ char smem[32768];
    char* bufA = smem;
    char* bufB = smem + 16384;

    const int tid  = threadIdx.x;
    const int wave = tid >> 6;
    const int lane = tid & 63;
    const int lhi  = lane >> 4;
    const int llo  = lane & 15;

    const long rowbase = (long)blockIdx.x * 128 + wave * 32;
    const char* gw = (const char*)g_wpack;

    auto stage1 = [&](char* dst, int kt) {     // 11264B (kt<8) / 9216B (kt=8)
        const char* w1b = gw + kt * 9216;
        const char* wib = gw + 164864 + kt * 2048;
        const int nb = (kt == 8) ? 9216 : 11264;
        #pragma unroll
        for (int k = 0; k < 3; ++k) {
            int b = k * 4096 + wave * 1024;
            if (b < nb) {
                const char* src = (b < 9216) ? (w1b + b) : (wib + (b - 9216));
                gl_lds16(src + lane * 16, dst + b);
            }
        }
    };
    auto stage16 = [&](char* dst, const char* src) {   // 16KB
        #pragma unroll
        for (int k = 0; k < 4; ++k) {
            int b = k * 4096 + wave * 1024;
            gl_lds16(src + b + lane * 16, dst + b);
        }
    };
    auto stage8 = [&](char* dst, const char* src) {    // 8KB
        #pragma unroll
        for (int k = 0; k < 2; ++k) {
            int b = k * 4096 + wave * 1024;
            gl_lds16(src + b + lane * 16, dst + b);
        }
    };

    // prologue: actions
    int i0[2], i1[2], i2[2];
    #pragma unroll
    for (int m = 0; m < 2; ++m) {
        long r = rowbase + m * 16 + llo;
        long f = r >> 6; int n = (int)(r & 63);
        i0[m] = act[(f * 3 + 0) * 64 + n];
        i1[m] = act[(f * 3 + 1) * 64 + n] + 8;
        i2[m] = act[(f * 3 + 2) * 64 + n] + 16;
    }

    const float4v fz = {0.f, 0.f, 0.f, 0.f};
    float4v acc1[2][9];      // h^T: lane holds h[m*16+llo][nt*16+lhi*4+r]
    float4v acc3[2][2];      // out1^T
    #pragma unroll
    for (int m = 0; m < 2; ++m) {
        #pragma unroll
        for (int n = 0; n < 9; ++n) acc1[m][n] = fz;
        acc3[m][0] = fz; acc3[m][1] = fz;
    }

    const float* cfb[2];
    #pragma unroll
    for (int m = 0; m < 2; ++m)
        cfb[m] = cf + (rowbase + m * 16 + llo) * 256 + lhi * 8;

    // ================= Phase 1: GEMM1(sw) + GEMM3a(sw) over cf ==============
    float4v pa0[2], pa1[2], pb0[2], pb1[2];
    stage1(bufA, 0);
    #pragma unroll
    for (int m = 0; m < 2; ++m) {
        pa0[m] = *(const float4v*)(cfb[m]);
        pa1[m] = *(const float4v*)(cfb[m] + 4);
        pb0[m] = *(const float4v*)(cfb[m] + 32);
        pb1[m] = *(const float4v*)(cfb[m] + 36);
    }
    __syncthreads();

    #pragma unroll 1
    for (int kt = 0; kt < 8; ++kt) {
        stage1((kt & 1) ? bufA : bufB, kt + 1);
        const char* wb = (kt & 1) ? bufB : bufA;
        short8 a[2];
        if (kt & 1) { a[0] = cvt8(pb0[0], pb1[0]); a[1] = cvt8(pb0[1], pb1[1]); }
        else        { a[0] = cvt8(pa0[0], pa1[0]); a[1] = cvt8(pa0[1], pa1[1]); }
        if (kt <= 5) {
            int o = (kt + 2) * 32;
            if (kt & 1) {
                #pragma unroll
                for (int m = 0; m < 2; ++m) {
                    pb0[m] = *(const float4v*)(cfb[m] + o);
                    pb1[m] = *(const float4v*)(cfb[m] + o + 4);
                }
            } else {
                #pragma unroll
                for (int m = 0; m < 2; ++m) {
                    pa0[m] = *(const float4v*)(cfb[m] + o);
                    pa1[m] = *(const float4v*)(cfb[m] + o + 4);
                }
            }
        }
        #pragma unroll
        for (int nt = 0; nt < 9; ++nt) {
            short8 bf = *(const short8*)(wb + (nt << 10) + (lane << 4));
            acc1[0][nt] = MFMA16(bf, a[0], acc1[0][nt], 0, 0, 0);   // swapped
            acc1[1][nt] = MFMA16(bf, a[1], acc1[1][nt], 0, 0, 0);
        }
        #pragma unroll
        for (int nt = 0; nt < 2; ++nt) {
            short8 bf = *(const short8*)(wb + ((9 + nt) << 10) + (lane << 4));
            acc3[0][nt] = MFMA16(bf, a[0], acc3[0][nt], 0, 0, 0);   // swapped
            acc3[1][nt] = MFMA16(bf, a[1], acc3[1][nt], 0, 0, 0);
        }
        __syncthreads();
    }
    // kt = 8: one-hot action K-tile (reads bufA, staged at kt=7)
    {
        short8 a[2];
        #pragma unroll
        for (int m = 0; m < 2; ++m) {
            #pragma unroll
            for (int i = 0; i < 8; ++i) {
                int kk = lhi * 8 + i;
                a[m][i] = (kk == i0[m] || kk == i1[m] || kk == i2[m])
                              ? (short)0x3F80 : (short)0;
            }
        }
        #pragma unroll
        for (int nt = 0; nt < 9; ++nt) {
            short8 bf = *(const short8*)(bufA + (nt << 10) + (lane << 4));
            acc1[0][nt] = MFMA16(bf, a[0], acc1[0][nt], 0, 0, 0);
            acc1[1][nt] = MFMA16(bf, a[1], acc1[1][nt], 0, 0, 0);
        }
    }
    __syncthreads();   // all staging reads done -> restage

    // ---- stage Wi-hi (16KB -> bufB) + W2T q0 (8KB -> bufA) ----
    stage16(bufB, gw + 164864 + 16384);
    stage8(bufA, gw + 82944);

    // ---- epilogue: acc1 -> hb[2][5] in regs (bias + leaky + cvt, pi-order) --
    short8 hb[2][5];
    #pragma unroll
    for (int kt = 0; kt < 5; ++kt) {
        int cLo = 2 * kt * 16 + lhi * 4;
        int cHi = (2 * kt + 1) * 16 + lhi * 4;
        if (cLo > 136) cLo = 136;          // nt=8,lhi=3: pad cols, bias inert
        float4v bLo = *(const float4v*)(b1 + cLo);
        float4v bHi = (kt < 4) ? *(const float4v*)(b1 + cHi) : fz;
        #pragma unroll
        for (int m = 0; m < 2; ++m) {
            union { int d[4]; short8 s; } t;
            float v0 = acc1[m][2 * kt][0] + bLo[0]; v0 = v0 > 0.f ? v0 : 0.1f * v0;
            float v1 = acc1[m][2 * kt][1] + bLo[1]; v1 = v1 > 0.f ? v1 : 0.1f * v1;
            float v2 = acc1[m][2 * kt][2] + bLo[2]; v2 = v2 > 0.f ? v2 : 0.1f * v2;
            float v3 = acc1[m][2 * kt][3] + bLo[3]; v3 = v3 > 0.f ? v3 : 0.1f * v3;
            t.d[0] = pk2(v0, v1);
            t.d[1] = pk2(v2, v3);
            if (kt < 4) {
                float w0 = acc1[m][2 * kt + 1][0] + bHi[0]; w0 = w0 > 0.f ? w0 : 0.1f * w0;
                float w1 = acc1[m][2 * kt + 1][1] + bHi[1]; w1 = w1 > 0.f ? w1 : 0.1f * w1;
                float w2 = acc1[m][2 * kt + 1][2] + bHi[2]; w2 = w2 > 0.f ? w2 : 0.1f * w2;
                float w3 = acc1[m][2 * kt + 1][3] + bHi[3]; w3 = w3 > 0.f ? w3 : 0.1f * w3;
                t.d[2] = pk2(w0, w1);
                t.d[3] = pk2(w2, w3);
            } else { t.d[2] = 0; t.d[3] = 0; }
            hb[m][kt] = t.s;
        }
    }

    // nf features for kt0/kt1
    const float* nfb[2];
    #pragma unroll
    for (int m = 0; m < 2; ++m)
        nfb[m] = nf + (rowbase + m * 16 + llo) * 256 + lhi * 8;
    #pragma unroll
    for (int m = 0; m < 2; ++m) {
        pa0[m] = *(const float4v*)(nfb[m]);
        pa1[m] = *(const float4v*)(nfb[m] + 4);
        pb0[m] = *(const float4v*)(nfb[m] + 32);
        pb1[m] = *(const float4v*)(nfb[m] + 36);
    }
    __syncthreads();                       // Wi-hi + W2T q0 visible

    // ================= Phase 2: GEMM3b(sw) over nf (no barriers) ============
    #pragma unroll 1
    for (int kt = 0; kt < 8; ++kt) {
        short8 a[2];
        if (kt & 1) { a[0] = cvt8(pb0[0], pb1[0]); a[1] = cvt8(pb0[1], pb1[1]); }
        else        { a[0] = cvt8(pa0[0], pa1[0]); a[1] = cvt8(pa0[1], pa1[1]); }
        if (kt <= 5) {
            int o = (kt + 2) * 32;
            if (kt & 1) {
                #pragma unroll
                for (int m = 0; m < 2; ++m) {
                    pb0[m] = *(const float4v*)(nfb[m] + o);
                    pb1[m] = *(const float4v*)(nfb[m] + o + 4);
                }
            } else {
                #pragma unroll
                for (int m = 0; m < 2; ++m) {
                    pa0[m] = *(const float4v*)(nfb[m] + o);
                    pa1[m] = *(const float4v*)(nfb[m] + o + 4);
                }
            }
        }
        #pragma unroll
        for (int nt = 0; nt < 2; ++nt) {
            int f = 2 * kt + nt;           // Wi-hi local frag 0..15
            short8 bf = *(const short8*)(bufB + (f << 10) + (lane << 4));
            acc3[0][nt] = MFMA16(bf, a[0], acc3[0][nt], 0, 0, 0);   // swapped
            acc3[1][nt] = MFMA16(bf, a[1], acc3[1][nt], 0, 0, 0);
        }
    }
    // out1^T stores: lane holds out1[row=grp+llo][nt*16+lhi*4+{0..3}]
    float* out2 = out + 67108864L;
    #pragma unroll
    for (int m = 0; m < 2; ++m) {
        #pragma unroll
        for (int nt = 0; nt < 2; ++nt) {
            if (nt == 0 || lhi < 2) {      // cols < 24 only
                float4v biv = *(const float4v*)(bi + nt * 16 + lhi * 4);
                long row = rowbase + m * 16 + llo;
                float4v v = acc3[m][nt];
                v[0] += biv[0]; v[1] += biv[1]; v[2] += biv[2]; v[3] += biv[3];
                *(float4v*)(out2 + row * 24 + nt * 16 + lhi * 4) = v;
            }
        }
    }
    __syncthreads();   // bufB reads done -> phase 3 may restage

    // ================= Phase 3: GEMM2 via pi-identity, 2 passes =============
    #pragma unroll 1
    for (int p = 0; p < 2; ++p) {
        float4v acc2[2][8];
        #pragma unroll
        for (int m = 0; m < 2; ++m)
            #pragma unroll
            for (int n = 0; n < 8; ++n) acc2[m][n] = fz;

        #pragma unroll
        for (int kt = 0; kt < 5; ++kt) {
            int q = p * 5 + kt;
            if (q < 9)
                stage8(((q + 1) & 1) ? bufB : bufA, gw + 82944 + (q + 1) * 8192);
            const char* wb = (q & 1) ? bufB : bufA;
            #pragma unroll
            for (int n = 0; n < 8; ++n) {
                short8 bf = *(const short8*)(wb + (n << 10) + (lane << 4));
                acc2[0][n] = MFMA16(bf, hb[0][kt], acc2[0][n], 0, 0, 0);
                acc2[1][n] = MFMA16(bf, hb[1][kt], acc2[1][n], 0, 0, 0);
            }
            if (q < 9) __syncthreads();
        }
        // out0^T stores: lane holds out0[row=grp+llo][nt*16+lhi*4+{0..3}]
        #pragma unroll
        for (int m = 0; m < 2; ++m) {
            #pragma unroll
            for (int n = 0; n < 8; ++n) {
                int nt = p * 8 + n;
                float4v b2v = *(const float4v*)(b2 + nt * 16 + lhi * 4);
                long row = rowbase + m * 16 + llo;
                float4v v = acc2[m][n];
                v[0] += b2v[0]; v[1] += b2v[1]; v[2] += b2v[2]; v[3] += b2v[3];
                *(float4v*)(out + row * 256 + nt * 16 + lhi * 4) = v;
            }
        }
    }
}

extern "C" void kernel_launch(void* const* d_in, const int* in_sizes, int n_in,
                              void* d_out, int out_size, void* d_ws, size_t ws_size,
                              hipStream_t stream) {
    const float *cf = nullptr, *nf = nullptr, *W1 = nullptr, *b1 = nullptr;
    const float *W2 = nullptr, *b2 = nullptr, *Wi = nullptr, *bi = nullptr;
    const int *ac = nullptr;
    for (int i = 0; i < n_in; ++i) {
        int s = in_sizes[i];
        const void* p = d_in[i];
        switch (s) {
            case 67108864: if (!cf) cf = (const float*)p; else nf = (const float*)p; break;
            case 786432:   ac = (const int*)p;   break;
            case 39200:    W1 = (const float*)p; break;
            case 140:      b1 = (const float*)p; break;
            case 35840:    W2 = (const float*)p; break;
            case 256:      b2 = (const float*)p; break;
            case 12288:    Wi = (const float*)p; break;
            case 24:       bi = (const float*)p; break;
            default: break;
        }
    }
    float* ob = (float*)d_out;

    pack_weights<<<386, 256, 0, stream>>>(W1, W2, Wi);
    icm_main<<<2048, 256, 0, stream>>>(cf, nf, ac, b1, b2, bi, ob);
}

// Round 15
// 223.836 us; speedup vs baseline: 1.3079x; 1.3079x over previous
//
#include <hip/hip_runtime.h>
#include <hip/hip_bf16.h>
#include <stdint.h>

// Round 15: r14's verified pi-identity design (h never materializes, 0 bank
// conflicts) with register pressure cut to fit launch_bounds(256,3) WITHOUT
// spills (r14's +64MB FETCH/+138MB WRITE spill signature):
//  - 1-deep feature prefetch (saves 16 regs in the peak phase)
//  - GEMM2 merged to one pass (acc2[2][16]); W2T packed kt-major, staged as
//    5x16KB (4 stage+barrier steps instead of 9)
// Math identical to r14 (PASS, absmax 0.03125).

typedef __attribute__((ext_vector_type(8))) short short8;
typedef __attribute__((ext_vector_type(4))) float float4v;

#define MFMA16 __builtin_amdgcn_mfma_f32_16x16x32_bf16

__device__ __align__(16) uint16_t g_wpack[98816];

static __device__ __forceinline__ void gl_lds16(const void* g, void* l) {
    __builtin_amdgcn_global_load_lds(
        (const __attribute__((address_space(1))) unsigned int*)g,
        (__attribute__((address_space(3))) unsigned int*)l, 16, 0, 0);
}

static __device__ __forceinline__ uint16_t f2bf(float f) {
    __hip_bfloat16 h = __float2bfloat16(f);
    return *reinterpret_cast<uint16_t*>(&h);
}

static __device__ __forceinline__ int pk2(float lo, float hi) {
    __hip_bfloat162 b = __float22bfloat162_rn(make_float2(lo, hi));
    int u; __builtin_memcpy(&u, &b, 4); return u;
}

static __device__ __forceinline__ short8 cvt8(float4v x0, float4v x1) {
    union { __hip_bfloat162 b2[4]; short8 s; } u;
    u.b2[0] = __float22bfloat162_rn(make_float2(x0[0], x0[1]));
    u.b2[1] = __float22bfloat162_rn(make_float2(x0[2], x0[3]));
    u.b2[2] = __float22bfloat162_rn(make_float2(x1[0], x1[1]));
    u.b2[3] = __float22bfloat162_rn(make_float2(x1[2], x1[3]));
    return u.s;
}

// ---- weight packing ----
// W1p: 9kt x 9nt std frags (K=288 pad, N=144 pad) @u16 0      (41472)
// W2Tp: pi-packed transposed, KT-MAJOR: frag = kt*16 + nt @u16 41472 (40960)
//       slot(lane,i) = W2[kt*32+(i>=4)*16+(lane>>4)*4+(i&3)][nt*16+(lane&15)]
// Wip: 16kt x 2nt std frags (K=512, N=32 pad) @u16 82432 (16384)
__global__ __launch_bounds__(256) void pack_weights(
    const float* __restrict__ W1, const float* __restrict__ W2,
    const float* __restrict__ Wi)
{
    int e = blockIdx.x * 256 + threadIdx.x;
    if (e >= 98816) return;
    if (e >= 41472 && e < 82432) {            // W2^T pi-packed, kt-major
        int le = e - 41472;
        int i = le & 7, lane = (le >> 3) & 63, frag = le >> 9;   // 0..79
        int kt = frag >> 4, nt = frag & 15;
        int k = kt * 32 + ((i >= 4) ? 16 : 0) + ((lane >> 4) << 2) + (i & 3);
        int n = nt * 16 + (lane & 15);
        float v = (k < 140) ? W2[k * 256 + n] : 0.0f;
        g_wpack[e] = f2bf(v);
        return;
    }
    const float* W; int NT, Kr, Nr, ld, le, base;
    if (e < 41472) { W = W1; NT = 9; Kr = 280; Nr = 140; ld = 140; le = e;         base = 0; }
    else           { W = Wi; NT = 2; Kr = 512; Nr = 24;  ld = 24;  le = e - 82432; base = 82432; }
    int i = le & 7, lane = (le >> 3) & 63, frag = le >> 9;
    int kt = frag / NT, nt = frag - kt * NT;
    int k = kt * 32 + ((lane >> 4) << 3) + i;
    int n = nt * 16 + (lane & 15);
    float v = (k < Kr && n < Nr) ? W[k * ld + n] : 0.0f;
    g_wpack[base + le] = f2bf(v);
}

// ---- main fused kernel: 256 threads = 4 waves, each wave 32 rows ----
__global__ __launch_bounds__(256, 3) void icm_main(
    const float* __restrict__ cf, const float* __restrict__ nf,
    const int* __restrict__ act,
    const float* __restrict__ b1, const float* __restrict__ b2,
    const float* __restrict__ bi,
    float* __restrict__ out)
{
    __shared__ char smem[32768];
    char* bufA = smem;
    char* bufB = smem + 16384;

    const int tid  = threadIdx.x;
    const int wave = tid >> 6;
    const int lane = tid & 63;
    const int lhi  = lane >> 4;
    const int llo  = lane & 15;

    const long rowbase = (long)blockIdx.x * 128 + wave * 32;
    const char* gw = (const char*)g_wpack;

    auto stage1 = [&](char* dst, int kt) {     // 11264B (kt<8) / 9216B (kt=8)
        const char* w1b = gw + kt * 9216;
        const char* wib = gw + 164864 + kt * 2048;
        const int nb = (kt == 8) ? 9216 : 11264;
        #pragma unroll
        for (int k = 0; k < 3; ++k) {
            int b = k * 4096 + wave * 1024;
            if (b < nb) {
                const char* src = (b < 9216) ? (w1b + b) : (wib + (b - 9216));
                gl_lds16(src + lane * 16, dst + b);
            }
        }
    };
    auto stage16 = [&](char* dst, const char* src) {   // 16KB
        #pragma unroll
        for (int k = 0; k < 4; ++k) {
            int b = k * 4096 + wave * 1024;
            gl_lds16(src + b + lane * 16, dst + b);
        }
    };

    // prologue: actions
    int i0[2], i1[2], i2[2];
    #pragma unroll
    for (int m = 0; m < 2; ++m) {
        long r = rowbase + m * 16 + llo;
        long f = r >> 6; int n = (int)(r & 63);
        i0[m] = act[(f * 3 + 0) * 64 + n];
        i1[m] = act[(f * 3 + 1) * 64 + n] + 8;
        i2[m] = act[(f * 3 + 2) * 64 + n] + 16;
    }

    const float4v fz = {0.f, 0.f, 0.f, 0.f};
    float4v acc1[2][9];      // h^T: lane holds h[m*16+llo][nt*16+lhi*4+r]
    float4v acc3[2][2];      // out1^T
    #pragma unroll
    for (int m = 0; m < 2; ++m) {
        #pragma unroll
        for (int n = 0; n < 9; ++n) acc1[m][n] = fz;
        acc3[m][0] = fz; acc3[m][1] = fz;
    }

    const float* cfb[2];
    #pragma unroll
    for (int m = 0; m < 2; ++m)
        cfb[m] = cf + (rowbase + m * 16 + llo) * 256 + lhi * 8;

    // ================= Phase 1: GEMM1(sw) + GEMM3a(sw) over cf ==============
    float4v pa0[2], pa1[2];
    stage1(bufA, 0);
    #pragma unroll
    for (int m = 0; m < 2; ++m) {
        pa0[m] = *(const float4v*)(cfb[m]);
        pa1[m] = *(const float4v*)(cfb[m] + 4);
    }
    __syncthreads();

    #pragma unroll 1
    for (int kt = 0; kt < 8; ++kt) {
        stage1((kt & 1) ? bufA : bufB, kt + 1);
        const char* wb = (kt & 1) ? bufB : bufA;
        short8 a[2];
        a[0] = cvt8(pa0[0], pa1[0]);
        a[1] = cvt8(pa0[1], pa1[1]);
        if (kt < 7) {                          // 1-deep refill
            int o = (kt + 1) * 32;
            #pragma unroll
            for (int m = 0; m < 2; ++m) {
                pa0[m] = *(const float4v*)(cfb[m] + o);
                pa1[m] = *(const float4v*)(cfb[m] + o + 4);
            }
        }
        #pragma unroll
        for (int nt = 0; nt < 9; ++nt) {
            short8 bf = *(const short8*)(wb + (nt << 10) + (lane << 4));
            acc1[0][nt] = MFMA16(bf, a[0], acc1[0][nt], 0, 0, 0);   // swapped
            acc1[1][nt] = MFMA16(bf, a[1], acc1[1][nt], 0, 0, 0);
        }
        #pragma unroll
        for (int nt = 0; nt < 2; ++nt) {
            short8 bf = *(const short8*)(wb + ((9 + nt) << 10) + (lane << 4));
            acc3[0][nt] = MFMA16(bf, a[0], acc3[0][nt], 0, 0, 0);   // swapped
            acc3[1][nt] = MFMA16(bf, a[1], acc3[1][nt], 0, 0, 0);
        }
        __syncthreads();
    }
    // kt = 8: one-hot action K-tile (reads bufA, staged at kt=7)
    {
        short8 a[2];
        #pragma unroll
        for (int m = 0; m < 2; ++m) {
            #pragma unroll
            for (int i = 0; i < 8; ++i) {
                int kk = lhi * 8 + i;
                a[m][i] = (kk == i0[m] || kk == i1[m] || kk == i2[m])
                              ? (short)0x3F80 : (short)0;
            }
        }
        #pragma unroll
        for (int nt = 0; nt < 9; ++nt) {
            short8 bf = *(const short8*)(bufA + (nt << 10) + (lane << 4));
            acc1[0][nt] = MFMA16(bf, a[0], acc1[0][nt], 0, 0, 0);
            acc1[1][nt] = MFMA16(bf, a[1], acc1[1][nt], 0, 0, 0);
        }
    }
    __syncthreads();   // all staging reads done -> restage

    // ---- stage Wi-hi (16KB -> bufB) + W2T kt0 (16KB -> bufA) ----
    stage16(bufB, gw + 164864 + 16384);
    stage16(bufA, gw + 82944);

    // ---- epilogue: acc1 -> hb[2][5] in regs (bias + leaky + cvt, pi-order) --
    short8 hb[2][5];
    #pragma unroll
    for (int kt = 0; kt < 5; ++kt) {
        int cLo = 2 * kt * 16 + lhi * 4;
        int cHi = (2 * kt + 1) * 16 + lhi * 4;
        if (cLo > 136) cLo = 136;          // nt=8,lhi=3: pad cols, inert
        float4v bLo = *(const float4v*)(b1 + cLo);
        float4v bHi = (kt < 4) ? *(const float4v*)(b1 + cHi) : fz;
        #pragma unroll
        for (int m = 0; m < 2; ++m) {
            union { int d[4]; short8 s; } t;
            float v0 = acc1[m][2 * kt][0] + bLo[0]; v0 = v0 > 0.f ? v0 : 0.1f * v0;
            float v1 = acc1[m][2 * kt][1] + bLo[1]; v1 = v1 > 0.f ? v1 : 0.1f * v1;
            float v2 = acc1[m][2 * kt][2] + bLo[2]; v2 = v2 > 0.f ? v2 : 0.1f * v2;
            float v3 = acc1[m][2 * kt][3] + bLo[3]; v3 = v3 > 0.f ? v3 : 0.1f * v3;
            t.d[0] = pk2(v0, v1);
            t.d[1] = pk2(v2, v3);
            if (kt < 4) {
                float w0 = acc1[m][2 * kt + 1][0] + bHi[0]; w0 = w0 > 0.f ? w0 : 0.1f * w0;
                float w1 = acc1[m][2 * kt + 1][1] + bHi[1]; w1 = w1 > 0.f ? w1 : 0.1f * w1;
                float w2 = acc1[m][2 * kt + 1][2] + bHi[2]; w2 = w2 > 0.f ? w2 : 0.1f * w2;
                float w3 = acc1[m][2 * kt + 1][3] + bHi[3]; w3 = w3 > 0.f ? w3 : 0.1f * w3;
                t.d[2] = pk2(w0, w1);
                t.d[3] = pk2(w2, w3);
            } else { t.d[2] = 0; t.d[3] = 0; }
            hb[m][kt] = t.s;
        }
    }

    // nf features for kt0
    const float* nfb[2];
    #pragma unroll
    for (int m = 0; m < 2; ++m)
        nfb[m] = nf + (rowbase + m * 16 + llo) * 256 + lhi * 8;
    #pragma unroll
    for (int m = 0; m < 2; ++m) {
        pa0[m] = *(const float4v*)(nfb[m]);
        pa1[m] = *(const float4v*)(nfb[m] + 4);
    }
    __syncthreads();                       // Wi-hi + W2T kt0 visible

    // ================= Phase 2: GEMM3b(sw) over nf (no barriers) ============
    #pragma unroll 1
    for (int kt = 0; kt < 8; ++kt) {
        short8 a[2];
        a[0] = cvt8(pa0[0], pa1[0]);
        a[1] = cvt8(pa0[1], pa1[1]);
        if (kt < 7) {
            int o = (kt + 1) * 32;
            #pragma unroll
            for (int m = 0; m < 2; ++m) {
                pa0[m] = *(const float4v*)(nfb[m] + o);
                pa1[m] = *(const float4v*)(nfb[m] + o + 4);
            }
        }
        #pragma unroll
        for (int nt = 0; nt < 2; ++nt) {
            int f = 2 * kt + nt;           // Wi-hi local frag 0..15
            short8 bf = *(const short8*)(bufB + (f << 10) + (lane << 4));
            acc3[0][nt] = MFMA16(bf, a[0], acc3[0][nt], 0, 0, 0);   // swapped
            acc3[1][nt] = MFMA16(bf, a[1], acc3[1][nt], 0, 0, 0);
        }
    }
    // out1^T stores: lane holds out1[row=grp+llo][nt*16+lhi*4+{0..3}]
    float* out2 = out + 67108864L;
    #pragma unroll
    for (int m = 0; m < 2; ++m) {
        #pragma unroll
        for (int nt = 0; nt < 2; ++nt) {
            if (nt == 0 || lhi < 2) {      // cols < 24 only
                float4v biv = *(const float4v*)(bi + nt * 16 + lhi * 4);
                long row = rowbase + m * 16 + llo;
                float4v v = acc3[m][nt];
                v[0] += biv[0]; v[1] += biv[1]; v[2] += biv[2]; v[3] += biv[3];
                *(float4v*)(out2 + row * 24 + nt * 16 + lhi * 4) = v;
            }
        }
    }
    __syncthreads();   // bufB reads done -> phase 3 may restage

    // ================= Phase 3: GEMM2 via pi-identity, single pass ==========
    float4v acc2[2][16];
    #pragma unroll
    for (int m = 0; m < 2; ++m)
        #pragma unroll
        for (int n = 0; n < 16; ++n) acc2[m][n] = fz;

    #pragma unroll 1
    for (int kt = 0; kt < 5; ++kt) {
        if (kt < 4)
            stage16((kt & 1) ? bufA : bufB, gw + 82944 + (kt + 1) * 16384);
        const char* wb = (kt & 1) ? bufB : bufA;
        #pragma unroll
        for (int n = 0; n < 16; ++n) {
            short8 bf = *(const short8*)(wb + (n << 10) + (lane << 4));
            acc2[0][n] = MFMA16(bf, hb[0][kt], acc2[0][n], 0, 0, 0);
            acc2[1][n] = MFMA16(bf, hb[1][kt], acc2[1][n], 0, 0, 0);
        }
        if (kt < 4) __syncthreads();
    }

    // out0^T stores: lane holds out0[row=grp+llo][nt*16+lhi*4+{0..3}]
    #pragma unroll
    for (int m = 0; m < 2; ++m) {
        #pragma unroll
        for (int n = 0; n < 16; ++n) {
            float4v b2v = *(const float4v*)(b2 + n * 16 + lhi * 4);
            long row = rowbase + m * 16 + llo;
            float4v v = acc2[m][n];
            v[0] += b2v[0]; v[1] += b2v[1]; v[2] += b2v[2]; v[3] += b2v[3];
            *(float4v*)(out + row * 256 + n * 16 + lhi * 4) = v;
        }
    }
}

extern "C" void kernel_launch(void* const* d_in, const int* in_sizes, int n_in,
                              void* d_out, int out_size, void* d_ws, size_t ws_size,
                              hipStream_t stream) {
    const float *cf = nullptr, *nf = nullptr, *W1 = nullptr, *b1 = nullptr;
    const float *W2 = nullptr, *b2 = nullptr, *Wi = nullptr, *bi = nullptr;
    const int *ac = nullptr;
    for (int i = 0; i < n_in; ++i) {
        int s = in_sizes[i];
        const void* p = d_in[i];
        switch (s) {
            case 67108864: if (!cf) cf = (const float*)p; else nf = (const float*)p; break;
            case 786432:   ac = (const int*)p;   break;
            case 39200:    W1 = (const float*)p; break;
            case 140:      b1 = (const float*)p; break;
            case 35840:    W2 = (const float*)p; break;
            case 256:      b2 = (const float*)p; break;
            case 12288:    Wi = (const float*)p; break;
            case 24:       bi = (const float*)p; break;
            default: break;
        }
    }
    float* ob = (float*)d_out;

    pack_weights<<<386, 256, 0, stream>>>(W1, W2, Wi);
    icm_main<<<2048, 256, 0, stream>>>(cf, nf, ac, b1, b2, bi, ob);
}

// Round 16
// 203.890 us; speedup vs baseline: 1.4359x; 1.0978x over previous
//
#include <hip/hip_runtime.h>
#include <hip/hip_bf16.h>
#include <stdint.h>

// Round 16: r14/r15's verified pi-identity math (h never in LDS, 0 bank
// conflicts) + WINDOWED staging: 3 kt-steps per barrier (phase 1), W2T in
// 32KB kt-pair windows (phase 3). Barriers/block: 17(r12) -> 7. Each
// __syncthreads costs a full vmcnt(0) drain (~900cyc); that count was the
// cost driver at 2 waves/SIMD. launch_bounds(256,2): no spill (r14/r15's
// +40..138MB FETCH/WRITE spill signature must vanish -> 267/287MB).
// LDS 2x33792=67584B (r9 proved >64KB static OK). Math identical (0.03125).

typedef __attribute__((ext_vector_type(8))) short short8;
typedef __attribute__((ext_vector_type(4))) float float4v;

#define MFMA16 __builtin_amdgcn_mfma_f32_16x16x32_bf16

__device__ __align__(16) uint16_t g_wpack[98816];

static __device__ __forceinline__ void gl_lds16(const void* g, void* l) {
    __builtin_amdgcn_global_load_lds(
        (const __attribute__((address_space(1))) unsigned int*)g,
        (__attribute__((address_space(3))) unsigned int*)l, 16, 0, 0);
}

static __device__ __forceinline__ uint16_t f2bf(float f) {
    __hip_bfloat16 h = __float2bfloat16(f);
    return *reinterpret_cast<uint16_t*>(&h);
}

static __device__ __forceinline__ int pk2(float lo, float hi) {
    __hip_bfloat162 b = __float22bfloat162_rn(make_float2(lo, hi));
    int u; __builtin_memcpy(&u, &b, 4); return u;
}

static __device__ __forceinline__ short8 cvt8(float4v x0, float4v x1) {
    union { __hip_bfloat162 b2[4]; short8 s; } u;
    u.b2[0] = __float22bfloat162_rn(make_float2(x0[0], x0[1]));
    u.b2[1] = __float22bfloat162_rn(make_float2(x0[2], x0[3]));
    u.b2[2] = __float22bfloat162_rn(make_float2(x1[0], x1[1]));
    u.b2[3] = __float22bfloat162_rn(make_float2(x1[2], x1[3]));
    return u.s;
}

// ---- weight packing (identical to r15) ----
// W1p: 9kt x 9nt std frags (K=288 pad, N=144 pad) @u16 0      (41472)
// W2Tp: pi-packed transposed, KT-MAJOR: frag = kt*16 + nt @u16 41472 (40960)
//       slot(lane,i) = W2[kt*32+(i>=4)*16+(lane>>4)*4+(i&3)][nt*16+(lane&15)]
// Wip: 16kt x 2nt std frags (K=512, N=32 pad) @u16 82432 (16384)
__global__ __launch_bounds__(256) void pack_weights(
    const float* __restrict__ W1, const float* __restrict__ W2,
    const float* __restrict__ Wi)
{
    int e = blockIdx.x * 256 + threadIdx.x;
    if (e >= 98816) return;
    if (e >= 41472 && e < 82432) {            // W2^T pi-packed, kt-major
        int le = e - 41472;
        int i = le & 7, lane = (le >> 3) & 63, frag = le >> 9;   // 0..79
        int kt = frag >> 4, nt = frag & 15;
        int k = kt * 32 + ((i >= 4) ? 16 : 0) + ((lane >> 4) << 2) + (i & 3);
        int n = nt * 16 + (lane & 15);
        float v = (k < 140) ? W2[k * 256 + n] : 0.0f;
        g_wpack[e] = f2bf(v);
        return;
    }
    const float* W; int NT, Kr, Nr, ld, le, base;
    if (e < 41472) { W = W1; NT = 9; Kr = 280; Nr = 140; ld = 140; le = e;         base = 0; }
    else           { W = Wi; NT = 2; Kr = 512; Nr = 24;  ld = 24;  le = e - 82432; base = 82432; }
    int i = le & 7, lane = (le >> 3) & 63, frag = le >> 9;
    int kt = frag / NT, nt = frag - kt * NT;
    int k = kt * 32 + ((lane >> 4) << 3) + i;
    int n = nt * 16 + (lane & 15);
    float v = (k < Kr && n < Nr) ? W[k * ld + n] : 0.0f;
    g_wpack[base + le] = f2bf(v);
}

// ---- main fused kernel: 256 threads = 4 waves, each wave 32 rows ----
__global__ __launch_bounds__(256, 2) void icm_main(
    const float* __restrict__ cf, const float* __restrict__ nf,
    const int* __restrict__ act,
    const float* __restrict__ b1, const float* __restrict__ b2,
    const float* __restrict__ bi,
    float* __restrict__ out)
{
    __shared__ char smem[67584];
    char* bufA = smem;
    char* bufB = smem + 33792;

    const int tid  = threadIdx.x;
    const int wave = tid >> 6;
    const int lane = tid & 63;
    const int lhi  = lane >> 4;
    const int llo  = lane & 15;

    const long rowbase = (long)blockIdx.x * 128 + wave * 32;
    const char* gw = (const char*)g_wpack;

    auto stage1 = [&](char* dst, int kt) {     // 11264B (kt<8) / 9216B (kt=8)
        const char* w1b = gw + kt * 9216;
        const char* wib = gw + 164864 + kt * 2048;
        const int nb = (kt == 8) ? 9216 : 11264;
        #pragma unroll
        for (int k = 0; k < 3; ++k) {
            int b = k * 4096 + wave * 1024;
            if (b < nb) {
                const char* src = (b < 9216) ? (w1b + b) : (wib + (b - 9216));
                gl_lds16(src + lane * 16, dst + b);
            }
        }
    };
    auto stage16 = [&](char* dst, const char* src) {
        #pragma unroll
        for (int k = 0; k < 4; ++k) {
            int b = k * 4096 + wave * 1024;
            gl_lds16(src + b + lane * 16, dst + b);
        }
    };
    auto stage32 = [&](char* dst, const char* src) {
        #pragma unroll
        for (int k = 0; k < 8; ++k) {
            int b = k * 4096 + wave * 1024;
            gl_lds16(src + b + lane * 16, dst + b);
        }
    };

    // prologue: actions
    int i0[2], i1[2], i2[2];
    #pragma unroll
    for (int m = 0; m < 2; ++m) {
        long r = rowbase + m * 16 + llo;
        long f = r >> 6; int n = (int)(r & 63);
        i0[m] = act[(f * 3 + 0) * 64 + n];
        i1[m] = act[(f * 3 + 1) * 64 + n] + 8;
        i2[m] = act[(f * 3 + 2) * 64 + n] + 16;
    }

    const float4v fz = {0.f, 0.f, 0.f, 0.f};
    float4v acc1[2][9];      // h^T: lane holds h[m*16+llo][nt*16+lhi*4+r]
    float4v acc3[2][2];      // out1^T
    #pragma unroll
    for (int m = 0; m < 2; ++m) {
        #pragma unroll
        for (int n = 0; n < 9; ++n) acc1[m][n] = fz;
        acc3[m][0] = fz; acc3[m][1] = fz;
    }

    const float* cfb[2];
    #pragma unroll
    for (int m = 0; m < 2; ++m)
        cfb[m] = cf + (rowbase + m * 16 + llo) * 256 + lhi * 8;

    float4v pa0[2], pa1[2], pb0[2], pb1[2];   // 2 rolling slots (even/odd kt)

    // phase-1 step: consume slot (kt&1), refill with kt+2 (if <=7), 11 MFMAs
    auto g1 = [&](const char* base, int kt) {
        short8 a[2];
        if (kt & 1) { a[0] = cvt8(pb0[0], pb1[0]); a[1] = cvt8(pb0[1], pb1[1]); }
        else        { a[0] = cvt8(pa0[0], pa1[0]); a[1] = cvt8(pa0[1], pa1[1]); }
        if (kt <= 5) {
            int o = (kt + 2) * 32;
            if (kt & 1) {
                #pragma unroll
                for (int m = 0; m < 2; ++m) {
                    pb0[m] = *(const float4v*)(cfb[m] + o);
                    pb1[m] = *(const float4v*)(cfb[m] + o + 4);
                }
            } else {
                #pragma unroll
                for (int m = 0; m < 2; ++m) {
                    pa0[m] = *(const float4v*)(cfb[m] + o);
                    pa1[m] = *(const float4v*)(cfb[m] + o + 4);
                }
            }
        }
        #pragma unroll
        for (int nt = 0; nt < 9; ++nt) {
            short8 bf = *(const short8*)(base + (nt << 10) + (lane << 4));
            acc1[0][nt] = MFMA16(bf, a[0], acc1[0][nt], 0, 0, 0);   // swapped
            acc1[1][nt] = MFMA16(bf, a[1], acc1[1][nt], 0, 0, 0);
        }
        #pragma unroll
        for (int nt = 0; nt < 2; ++nt) {
            short8 bf = *(const short8*)(base + ((9 + nt) << 10) + (lane << 4));
            acc3[0][nt] = MFMA16(bf, a[0], acc3[0][nt], 0, 0, 0);   // swapped
            acc3[1][nt] = MFMA16(bf, a[1], acc3[1][nt], 0, 0, 0);
        }
    };

    // ===== pre-stage window0 (kts 0-2 -> bufA) + features kt0,kt1 =====
    stage1(bufA, 0); stage1(bufA + 11264, 1); stage1(bufA + 22528, 2);
    #pragma unroll
    for (int m = 0; m < 2; ++m) {
        pa0[m] = *(const float4v*)(cfb[m]);
        pa1[m] = *(const float4v*)(cfb[m] + 4);
        pb0[m] = *(const float4v*)(cfb[m] + 32);
        pb1[m] = *(const float4v*)(cfb[m] + 36);
    }
    __syncthreads();                                        // bar 1

    // ===== w0: compute kts 0-2 from bufA; stage kts 3-5 -> bufB =====
    stage1(bufB, 3); stage1(bufB + 11264, 4); stage1(bufB + 22528, 5);
    g1(bufA, 0); g1(bufA + 11264, 1); g1(bufA + 22528, 2);
    __syncthreads();                                        // bar 2

    // ===== w1: compute kts 3-5 from bufB; stage kts 6-8 -> bufA =====
    stage1(bufA, 6); stage1(bufA + 11264, 7); stage1(bufA + 22528, 8);
    g1(bufB, 3); g1(bufB + 11264, 4); g1(bufB + 22528, 5);
    __syncthreads();                                        // bar 3

    // ===== w2: compute kts 6,7 + one-hot(8) from bufA; stage Wi-hi -> bufB ==
    stage16(bufB, gw + 164864 + 16384);
    g1(bufA, 6); g1(bufA + 11264, 7);
    // nf features for phase 2 (slots now free)
    const float* nfb[2];
    #pragma unroll
    for (int m = 0; m < 2; ++m)
        nfb[m] = nf + (rowbase + m * 16 + llo) * 256 + lhi * 8;
    #pragma unroll
    for (int m = 0; m < 2; ++m) {
        pa0[m] = *(const float4v*)(nfb[m]);
        pa1[m] = *(const float4v*)(nfb[m] + 4);
        pb0[m] = *(const float4v*)(nfb[m] + 32);
        pb1[m] = *(const float4v*)(nfb[m] + 36);
    }
    {   // kt = 8: one-hot action K-tile
        short8 a[2];
        #pragma unroll
        for (int m = 0; m < 2; ++m) {
            #pragma unroll
            for (int i = 0; i < 8; ++i) {
                int kk = lhi * 8 + i;
                a[m][i] = (kk == i0[m] || kk == i1[m] || kk == i2[m])
                              ? (short)0x3F80 : (short)0;
            }
        }
        const char* base = bufA + 22528;
        #pragma unroll
        for (int nt = 0; nt < 9; ++nt) {
            short8 bf = *(const short8*)(base + (nt << 10) + (lane << 4));
            acc1[0][nt] = MFMA16(bf, a[0], acc1[0][nt], 0, 0, 0);
            acc1[1][nt] = MFMA16(bf, a[1], acc1[1][nt], 0, 0, 0);
        }
    }
    __syncthreads();                                        // bar 4

    // ===== phase 2: GEMM3b from bufB; stage W2T kts 0,1 -> bufA =====
    stage32(bufA, gw + 82944);

    // epilogue: acc1 -> hb (bias + leaky + cvt), overlaps staging
    short8 hb[2][5];
    #pragma unroll
    for (int kt = 0; kt < 5; ++kt) {
        int cLo = 2 * kt * 16 + lhi * 4;
        int cHi = (2 * kt + 1) * 16 + lhi * 4;
        if (cLo > 136) cLo = 136;          // nt=8,lhi=3: pad cols, inert
        float4v bLo = *(const float4v*)(b1 + cLo);
        float4v bHi = (kt < 4) ? *(const float4v*)(b1 + cHi) : fz;
        #pragma unroll
        for (int m = 0; m < 2; ++m) {
            union { int d[4]; short8 s; } t;
            float v0 = acc1[m][2 * kt][0] + bLo[0]; v0 = v0 > 0.f ? v0 : 0.1f * v0;
            float v1 = acc1[m][2 * kt][1] + bLo[1]; v1 = v1 > 0.f ? v1 : 0.1f * v1;
            float v2 = acc1[m][2 * kt][2] + bLo[2]; v2 = v2 > 0.f ? v2 : 0.1f * v2;
            float v3 = acc1[m][2 * kt][3] + bLo[3]; v3 = v3 > 0.f ? v3 : 0.1f * v3;
            t.d[0] = pk2(v0, v1);
            t.d[1] = pk2(v2, v3);
            if (kt < 4) {
                float w0 = acc1[m][2 * kt + 1][0] + bHi[0]; w0 = w0 > 0.f ? w0 : 0.1f * w0;
                float w1 = acc1[m][2 * kt + 1][1] + bHi[1]; w1 = w1 > 0.f ? w1 : 0.1f * w1;
                float w2 = acc1[m][2 * kt + 1][2] + bHi[2]; w2 = w2 > 0.f ? w2 : 0.1f * w2;
                float w3 = acc1[m][2 * kt + 1][3] + bHi[3]; w3 = w3 > 0.f ? w3 : 0.1f * w3;
                t.d[2] = pk2(w0, w1);
                t.d[3] = pk2(w2, w3);
            } else { t.d[2] = 0; t.d[3] = 0; }
            hb[m][kt] = t.s;
        }
    }

    #pragma unroll 1
    for (int kt = 0; kt < 8; ++kt) {
        short8 a[2];
        if (kt & 1) { a[0] = cvt8(pb0[0], pb1[0]); a[1] = cvt8(pb0[1], pb1[1]); }
        else        { a[0] = cvt8(pa0[0], pa1[0]); a[1] = cvt8(pa0[1], pa1[1]); }
        if (kt <= 5) {
            int o = (kt + 2) * 32;
            if (kt & 1) {
                #pragma unroll
                for (int m = 0; m < 2; ++m) {
                    pb0[m] = *(const float4v*)(nfb[m] + o);
                    pb1[m] = *(const float4v*)(nfb[m] + o + 4);
                }
            } else {
                #pragma unroll
                for (int m = 0; m < 2; ++m) {
                    pa0[m] = *(const float4v*)(nfb[m] + o);
                    pa1[m] = *(const float4v*)(nfb[m] + o + 4);
                }
            }
        }
        #pragma unroll
        for (int nt = 0; nt < 2; ++nt) {
            int f = 2 * kt + nt;           // Wi-hi local frag 0..15
            short8 bf = *(const short8*)(bufB + (f << 10) + (lane << 4));
            acc3[0][nt] = MFMA16(bf, a[0], acc3[0][nt], 0, 0, 0);   // swapped
            acc3[1][nt] = MFMA16(bf, a[1], acc3[1][nt], 0, 0, 0);
        }
    }
    // out1^T stores
    float* out2 = out + 67108864L;
    #pragma unroll
    for (int m = 0; m < 2; ++m) {
        #pragma unroll
        for (int nt = 0; nt < 2; ++nt) {
            if (nt == 0 || lhi < 2) {      // cols < 24 only
                float4v biv = *(const float4v*)(bi + nt * 16 + lhi * 4);
                long row = rowbase + m * 16 + llo;
                float4v v = acc3[m][nt];
                v[0] += biv[0]; v[1] += biv[1]; v[2] += biv[2]; v[3] += biv[3];
                *(float4v*)(out2 + row * 24 + nt * 16 + lhi * 4) = v;
            }
        }
    }
    __syncthreads();                                        // bar 5

    // ===== phase 3: GEMM2 via pi-identity, kt-pair windows =====
    float4v acc2[2][16];
    #pragma unroll
    for (int m = 0; m < 2; ++m)
        #pragma unroll
        for (int n = 0; n < 16; ++n) acc2[m][n] = fz;

    // w0: compute kts 0,1 from bufA; stage kts 2,3 -> bufB
    stage32(bufB, gw + 82944 + 32768);
    #pragma unroll
    for (int k = 0; k < 2; ++k) {
        const char* base = bufA + (k << 14);
        #pragma unroll
        for (int n = 0; n < 16; ++n) {
            short8 bf = *(const short8*)(base + (n << 10) + (lane << 4));
            acc2[0][n] = MFMA16(bf, hb[0][k], acc2[0][n], 0, 0, 0);
            acc2[1][n] = MFMA16(bf, hb[1][k], acc2[1][n], 0, 0, 0);
        }
    }
    __syncthreads();                                        // bar 6

    // w1: compute kts 2,3 from bufB; stage kt 4 -> bufA
    stage16(bufA, gw + 82944 + 65536);
    #pragma unroll
    for (int k = 0; k < 2; ++k) {
        const char* base = bufB + (k << 14);
        #pragma unroll
        for (int n = 0; n < 16; ++n) {
            short8 bf = *(const short8*)(base + (n << 10) + (lane << 4));
            acc2[0][n] = MFMA16(bf, hb[0][2 + k], acc2[0][n], 0, 0, 0);
            acc2[1][n] = MFMA16(bf, hb[1][2 + k], acc2[1][n], 0, 0, 0);
        }
    }
    __syncthreads();                                        // bar 7

    // w2: compute kt 4 from bufA
    #pragma unroll
    for (int n = 0; n < 16; ++n) {
        short8 bf = *(const short8*)(bufA + (n << 10) + (lane << 4));
        acc2[0][n] = MFMA16(bf, hb[0][4], acc2[0][n], 0, 0, 0);
        acc2[1][n] = MFMA16(bf, hb[1][4], acc2[1][n], 0, 0, 0);
    }

    // out0^T stores: lane holds out0[row=grp+llo][n*16+lhi*4+{0..3}]
    #pragma unroll
    for (int m = 0; m < 2; ++m) {
        #pragma unroll
        for (int n = 0; n < 16; ++n) {
            float4v b2v = *(const float4v*)(b2 + n * 16 + lhi * 4);
            long row = rowbase + m * 16 + llo;
            float4v v = acc2[m][n];
            v[0] += b2v[0]; v[1] += b2v[1]; v[2] += b2v[2]; v[3] += b2v[3];
            *(float4v*)(out + row * 256 + n * 16 + lhi * 4) = v;
        }
    }
}

extern "C" void kernel_launch(void* const* d_in, const int* in_sizes, int n_in,
                              void* d_out, int out_size, void* d_ws, size_t ws_size,
                              hipStream_t stream) {
    const float *cf = nullptr, *nf = nullptr, *W1 = nullptr, *b1 = nullptr;
    const float *W2 = nullptr, *b2 = nullptr, *Wi = nullptr, *bi = nullptr;
    const int *ac = nullptr;
    for (int i = 0; i < n_in; ++i) {
        int s = in_sizes[i];
        const void* p = d_in[i];
        switch (s) {
            case 67108864: if (!cf) cf = (const float*)p; else nf = (const float*)p; break;
            case 786432:   ac = (const int*)p;   break;
            case 39200:    W1 = (const float*)p; break;
            case 140:      b1 = (const float*)p; break;
            case 35840:    W2 = (const float*)p; break;
            case 256:      b2 = (const float*)p; break;
            case 12288:    Wi = (const float*)p; break;
            case 24:       bi = (const float*)p; break;
            default: break;
        }
    }
    float* ob = (float*)d_out;

    pack_weights<<<386, 256, 0, stream>>>(W1, W2, Wi);
    icm_main<<<2048, 256, 0, stream>>>(cf, nf, ac, b1, b2, bi, ob);
}